// Round 16
// baseline (483.781 us; speedup 1.0000x reference)
//
#include <hip/hip_runtime.h>
#include <hip/hip_bf16.h>

// Problem constants
#define BB 32
#define C1 128
#define SS 1024        // H*W
#define DD 256
#define NHH 8
#define DHH 32
#define KSEL 66        // ceil(0.0005*128*32*32)
#define TRIPLE 768
#define NTOK 80        // sparse-token capacity per batch (>= 66 + tie margin)
#define SCAPS 128      // survivor capacity
#define CCAP 2048      // candidate capacity per batch
#define DMAX (32 + NTOK)        // 112 tokens max per batch
#define PEROW (BB * NTOK)       // 2560: index of first PE row in E/SQKV
#define SELFLAG 0x40000000u

typedef __attribute__((ext_vector_type(8))) short bf16x8;
typedef __attribute__((ext_vector_type(4))) float f32x4;

__device__ inline short f2bf(float f) {
  union { __hip_bfloat16 h; unsigned short u; } c;
  c.h = __float2bfloat16(f);
  return (short)c.u;
}
__device__ inline float pe_val(int w, int d) {
  int i2 = d >> 1;
  float dv = expf((float)(2 * i2) * (-9.210340371976184f / 256.f));
  float ang = (float)w * dv;
  return (d & 1) ? cosf(ang) : sinf(ang);
}
__device__ inline unsigned aload_u(const unsigned* p) {
  return __hip_atomic_load(p, __ATOMIC_RELAXED, __HIP_MEMORY_SCOPE_AGENT);
}
__device__ inline float aload_f(const float* p) {
  return __hip_atomic_load(p, __ATOMIC_RELAXED, __HIP_MEMORY_SCOPE_AGENT);
}
__device__ inline void astore_u(unsigned* p, unsigned v) {
  __hip_atomic_store(p, v, __ATOMIC_RELAXED, __HIP_MEMORY_SCOPE_AGENT);
}
__device__ inline void astore_f(float* p, float v) {
  __hip_atomic_store(p, v, __ATOMIC_RELAXED, __HIP_MEMORY_SCOPE_AGENT);
}

// ---------------------------------------------------------------------------
// Kernel 0: zero ghist1 + ctx + all scalars/counters (one block per batch).
// ---------------------------------------------------------------------------
__global__ __launch_bounds__(256) void zero_kernel(
    unsigned* __restrict__ ghist1, unsigned* __restrict__ selv,
    unsigned* __restrict__ gmaxb, unsigned* __restrict__ cnd_n,
    unsigned* __restrict__ ccnt, unsigned* __restrict__ gcnt,
    unsigned* __restrict__ acnt, float* __restrict__ ctx) {
  const int b = blockIdx.x, t = threadIdx.x;
  uint4* g = (uint4*)(ghist1 + b * 2048);
  uint4 z = {0u, 0u, 0u, 0u};
  g[t] = z;
  g[t + 256] = z;
  ctx[b * DD + t] = 0.f;
  if (t == 0) {
    selv[b] = 0u; gmaxb[b] = 0u; cnd_n[b * 32] = 0u;
    ccnt[b * 32] = 0u; gcnt[b * 32] = 0u; acnt[b * 32] = 0u;
  }
}

// ---------------------------------------------------------------------------
// Kernel 1: 9x9 conv + ReLU + fused level-1 radix histogram + per-batch max
// + default topi fill + out_sw zero.  FAN-IN: last block per batch (ccnt==63)
// runs the level-1 radix pick (suffix scan) and writes selv[b].
// ---------------------------------------------------------------------------
__global__ __launch_bounds__(256) void conv_relu_hist_kernel(
    const float* __restrict__ x, const float* __restrict__ w, float* __restrict__ A,
    unsigned* __restrict__ ghist1, unsigned* __restrict__ gmaxb,
    float* __restrict__ out_topi, float* __restrict__ out_sw,
    unsigned* __restrict__ ccnt, unsigned* __restrict__ selv) {
  const int bx = blockIdx.x;              // b*64 + cpair
  const int b = bx >> 6, c0 = (bx & 63) * 2;
  __shared__ float xs[40 * 40];
  __shared__ unsigned h[2048];
  __shared__ unsigned gsum[256];
  __shared__ unsigned smax;
  __shared__ unsigned lastf;
  const int t = threadIdx.x;
  // zero out_sw: 2048 blocks x 2048 floats each
  {
    float4 z = {0.f, 0.f, 0.f, 0.f};
    float4* sw4 = (float4*)(out_sw + (size_t)bx * 2048);
    sw4[t] = z;
    sw4[t + 256] = z;
  }
  if (bx < 256) {
    int k0 = bx * 1024 + t * 4;
    float4 v = (k0 & 4) ? make_float4(4.f, 5.f, 6.f, 7.f)
                        : make_float4(0.f, 1.f, 2.f, 3.f);
    *(float4*)&out_topi[k0] = v;
  }
  for (int i = t; i < 1600; i += 256) {
    int r = i / 40, cc = i - r * 40;
    int gi = r - 4, gj = cc - 4;
    float v = 0.f;
    if (gi >= 0 && gi < 32 && gj >= 0 && gj < 32) v = x[(size_t)b * 1024 + gi * 32 + gj];
    xs[i] = v;
  }
  for (int i = t; i < 2048; i += 256) h[i] = 0u;
  if (t == 0) smax = 0u;
  __syncthreads();
  const float* w0 = w + (size_t)c0 * 81;   // block-uniform -> s_load
  const float* w1 = w0 + 81;
  const int r = t >> 3, cbase = (t & 7) * 4;
  const float4* xs4 = (const float4*)xs;
  float a0 = 0.f, a1 = 0.f, a2 = 0.f, a3 = 0.f;
  float b0 = 0.f, b1 = 0.f, b2 = 0.f, b3 = 0.f;
#pragma unroll
  for (int u = 0; u < 9; ++u) {
    int base4 = (r + u) * 10 + (t & 7);
    float4 xA = xs4[base4];
    float4 xB = xs4[base4 + 1];
    float4 xC = xs4[base4 + 2];
    float xv[12] = {xA.x, xA.y, xA.z, xA.w, xB.x, xB.y, xB.z, xB.w,
                    xC.x, xC.y, xC.z, xC.w};
#pragma unroll
    for (int v = 0; v < 9; ++v) {
      float f0 = w0[u * 9 + v], f1 = w1[u * 9 + v];
      a0 += f0 * xv[v];     a1 += f0 * xv[v + 1];
      a2 += f0 * xv[v + 2]; a3 += f0 * xv[v + 3];
      b0 += f1 * xv[v];     b1 += f1 * xv[v + 1];
      b2 += f1 * xv[v + 2]; b3 += f1 * xv[v + 3];
    }
  }
  a0 = fmaxf(a0, 0.f); a1 = fmaxf(a1, 0.f); a2 = fmaxf(a2, 0.f); a3 = fmaxf(a3, 0.f);
  b0 = fmaxf(b0, 0.f); b1 = fmaxf(b1, 0.f); b2 = fmaxf(b2, 0.f); b3 = fmaxf(b3, 0.f);
  float4 va = {a0, a1, a2, a3}, vb = {b0, b1, b2, b3};
  *(float4*)&A[((size_t)(b * C1 + c0) << 10) + r * 32 + cbase] = va;
  *(float4*)&A[((size_t)(b * C1 + c0 + 1) << 10) + r * 32 + cbase] = vb;
  unsigned lmax = 0u;
#pragma unroll
  for (int k = 0; k < 8; ++k) {
    float f = (k == 0) ? a0 : (k == 1) ? a1 : (k == 2) ? a2 : (k == 3) ? a3
            : (k == 4) ? b0 : (k == 5) ? b1 : (k == 6) ? b2 : b3;
    unsigned bits = __float_as_uint(f);
    if (bits > lmax) lmax = bits;
    if (bits >= (1u << 21)) atomicAdd(&h[bits >> 21], 1u);
  }
  atomicMax(&smax, lmax);
  __syncthreads();
  for (int i = t; i < 2048; i += 256)
    if (h[i]) atomicAdd(&ghist1[b * 2048 + i], h[i]);
  if (t == 0) atomicMax(&gmaxb[b], smax);
  // ---- fan-in: last block of batch b runs the level-1 radix pick ----
  __threadfence();
  if (t == 0) lastf = atomicAdd(&ccnt[b * 32], 1u);
  __syncthreads();
  if (lastf != 63u) return;
  for (int i = t; i < 2048; i += 256)
    h[i] = aload_u(&ghist1[b * 2048 + i]);
  __syncthreads();
  unsigned hv[8], T = 0;
#pragma unroll
  for (int k = 0; k < 8; ++k) { hv[k] = h[t * 8 + k]; T += hv[k]; }
  gsum[t] = T;
  __syncthreads();
  for (int off = 1; off < 256; off <<= 1) {
    unsigned v = (t + off < 256) ? gsum[t + off] : 0u;
    __syncthreads();
    gsum[t] += v;
    __syncthreads();
  }
  if (gsum[0] < (unsigned)KSEL) {
    if (t == 0) selv[b] = SELFLAG;
    return;
  }
  unsigned run = (t < 255) ? gsum[t + 1] : 0u;
#pragma unroll
  for (int k = 7; k >= 0; --k) {
    unsigned Sb = run + hv[k];
    if (run < (unsigned)KSEL && Sb >= (unsigned)KSEL) selv[b] = (unsigned)(t * 8 + k);
    run = Sb;
  }
}

// ---------------------------------------------------------------------------
// Kernel 2: candidate gather (block-aggregated compaction, agent-scope
// stores).  FAN-IN: last block per batch (gcnt==63) runs the full
// sparse-pixel processing (rank-count survivors, bitmap slots, scatter).
// ---------------------------------------------------------------------------
__global__ __launch_bounds__(256) void gather_kernel(
    const float* __restrict__ A, const unsigned* __restrict__ selv,
    unsigned* __restrict__ cnd_n, float* __restrict__ candv,
    unsigned* __restrict__ candloc, unsigned* __restrict__ gcnt,
    const unsigned* __restrict__ gmaxb, float* __restrict__ out_sw,
    float* __restrict__ out_topi, int* __restrict__ kidx8,
    float* __restrict__ kval8, unsigned* __restrict__ glist,
    unsigned* __restrict__ nswb, unsigned* __restrict__ npix) {
  const int b = blockIdx.y, slice = blockIdx.x, t = threadIdx.x;  // slice 0..63
  __shared__ float lv[512];
  __shared__ unsigned ll[512];
  __shared__ unsigned lcnt, gbase, glast;
  __shared__ float cv[CCAP];
  __shared__ unsigned cl[CCAP];
  __shared__ float sv[SCAPS];
  __shared__ int sch[SCAPS], spx[SCAPS];
  __shared__ int s_n_sh;
  __shared__ unsigned pixbit[32];
  __shared__ int mcount[NTOK];
  __shared__ int leadp[NTOK];
  const unsigned v1 = selv[b];
  if (v1 != SELFLAG) {
    if (t == 0) lcnt = 0u;
    __syncthreads();
    const unsigned thr = v1 << 21;        // bits>>21 >= v1  <=>  bits >= thr
    const float4* Ab = (const float4*)(A + (size_t)b * (C1 * SS) + slice * 2048);
    const float4 va = Ab[t];
    const float4 vb = Ab[t + 256];
    const int base = slice * 2048 + t * 4;
    const float f[8] = {va.x, va.y, va.z, va.w, vb.x, vb.y, vb.z, vb.w};
#pragma unroll
    for (int c = 0; c < 8; ++c) {
      if (__float_as_uint(f[c]) >= thr) {
        unsigned loc = (unsigned)(base + (c < 4 ? c : 1020 + c));   // c*1024 + p
        unsigned s = atomicAdd(&lcnt, 1u);
        if (s < 512u) {
          lv[s] = f[c];
          ll[s] = loc;
        } else {                           // overflow spill (degenerate inputs)
          unsigned g = atomicAdd(&cnd_n[b * 32], 1u);
          if (g < (unsigned)CCAP) {
            astore_f(&candv[b * CCAP + g], f[c]);
            astore_u(&candloc[b * CCAP + g], loc);
          }
        }
      }
    }
    __syncthreads();
    const unsigned cnt = lcnt < 512u ? lcnt : 512u;
    if (t == 0 && cnt) gbase = atomicAdd(&cnd_n[b * 32], cnt);
    __syncthreads();
    for (unsigned u = t; u < cnt; u += 256) {
      unsigned s = gbase + u;
      if (s < (unsigned)CCAP) {
        astore_f(&candv[b * CCAP + s], lv[u]);
        astore_u(&candloc[b * CCAP + s], ll[u]);
      }
    }
  }
  // ---- fan-in: last block of batch b runs sparse-pixel processing ----
  __threadfence();
  if (t == 0) glast = atomicAdd(&gcnt[b * 32], 1u);
  __syncthreads();
  if (glast != 63u) return;
  if (t == 0) s_n_sh = 0;
  if (t < 32) pixbit[t] = 0u;
  unsigned n = aload_u(&cnd_n[b * 32]);
  if (n > (unsigned)CCAP) n = (unsigned)CCAP;
  const bool ok = (v1 != SELFLAG) && (n >= (unsigned)KSEL);
  for (unsigned i = t; i < n; i += 256) {
    cv[i] = aload_f(&candv[b * CCAP + i]);
    cl[i] = aload_u(&candloc[b * CCAP + i]);
  }
  __syncthreads();
  if (ok) {
    for (unsigned i = t; i < n; i += 256) {
      float v = cv[i];
      int g = 0;
      for (unsigned j = 0; j < n; ++j) g += (cv[j] > v);
      if (g < KSEL) {
        int k = atomicAdd(&s_n_sh, 1);
        if (k < SCAPS) {
          sv[k] = v;
          sch[k] = (int)(cl[i] >> 10);
          spx[k] = (int)(cl[i] & 1023u);
        }
      }
    }
  }
  __syncthreads();
  const int s_n = s_n_sh < SCAPS ? s_n_sh : SCAPS;
  for (int i = t; i < s_n; i += 256)
    atomicOr(&pixbit[spx[i] >> 5], 1u << (spx[i] & 31));
  __syncthreads();
  if (t == 0) {
    int np = 0;
#pragma unroll
    for (int wd = 0; wd < 32; ++wd) np += __popc(pixbit[wd]);
    npix[b] = (unsigned)(np < NTOK ? np : NTOK);
  }
  if (t < 32) {
    unsigned cnt2 = 0;
#pragma unroll
    for (int rr = 0; rr < 32; ++rr) cnt2 += (pixbit[rr] >> t) & 1u;
    nswb[b * 32 + t] = cnt2;
  }
  const float gm = __uint_as_float(gmaxb[b]);
  const float scale = gm > 0.f ? 1.f / gm : 0.f;
  __syncthreads();
  for (int i = t; i < s_n; i += 256) {
    const int p = spx[i];
    const float v = sv[i];
    const int c = sch[i];
    const int word = p >> 5, bit = p & 31;
    int slot = 0;
    for (int wd = 0; wd < word; ++wd) slot += __popc(pixbit[wd]);
    slot += __popc(pixbit[word] & (bit ? ((1u << bit) - 1u) : 0u));
    if (slot >= NTOK) continue;
    int rank = 0, cntp = 0;
    for (int j = 0; j < s_n; ++j) {
      if (spx[j] != p) continue;
      ++cntp;
      rank += (sv[j] > v || (sv[j] == v && sch[j] < c));
    }
    const size_t pix = (size_t)b * SS + p;
    const float sval = v * scale;
    if (rank < 8) {
      out_topi[pix * 8 + rank] = (float)c;
      out_sw[pix * C1 + c] = sval;
      kidx8[((size_t)b * NTOK + slot) * 8 + rank] = c;
      kval8[((size_t)b * NTOK + slot) * 8 + rank] = sval;
    }
    if (rank == 0) {
      glist[b * NTOK + slot] =
          ((unsigned)b << 16) | ((unsigned)slot << 8) | (unsigned)(p & 31);
      mcount[slot] = cntp < 8 ? cntp : 8;
      leadp[slot] = p;
    }
  }
  __syncthreads();
  const int np = (int)npix[b];
  for (int s = t; s < np; s += 256) {
    const int m = mcount[s];
    if (m >= 8) continue;
    const int p = leadp[s];
    int used[8];
    for (int k = 0; k < m; ++k) used[k] = kidx8[((size_t)b * NTOK + s) * 8 + k];
    int fill_c = 0;
    for (int j = m; j < 8; ++j) {
      bool adv = true;
      while (adv) {
        adv = false;
        for (int k = 0; k < m; ++k)
          if (used[k] == fill_c) adv = true;
        if (adv) ++fill_c;
      }
      kidx8[((size_t)b * NTOK + s) * 8 + j] = fill_c;
      kval8[((size_t)b * NTOK + s) * 8 + j] = 0.f;
      out_topi[((size_t)b * SS + p) * 8 + j] = (float)fill_c;
      ++fill_c;
    }
  }
}

// ---------------------------------------------------------------------------
// Kernel 3: E rows.  Sparse token rows: PE(w) + sum_j kval8[j]*emb[kidx8[j]];
// rows PEROW..PEROW+31: pure PE(w).
// ---------------------------------------------------------------------------
__global__ __launch_bounds__(256) void emb_build_kernel(
    const unsigned* __restrict__ npix, const int* __restrict__ kidx8,
    const float* __restrict__ kval8, const unsigned* __restrict__ glist,
    const float* __restrict__ emb, float* __restrict__ E) {
  const int bx = blockIdx.x;              // b*NTOK + i, or PEROW + w
  const int d = threadIdx.x;
  if (bx >= PEROW) {
    E[(size_t)bx * DD + d] = pe_val(bx - PEROW, d);
    return;
  }
  const int b = bx / NTOK, i = bx - b * NTOK;
  if ((unsigned)i >= npix[b]) return;
  const int w = (int)(glist[bx] & 255u);
  const int* ki = kidx8 + (size_t)bx * 8;
  const float* kv = kval8 + (size_t)bx * 8;
  float e = pe_val(w, d);
#pragma unroll
  for (int j = 0; j < 8; ++j) e += kv[j] * emb[(size_t)ki[j] * DD + d];
  E[(size_t)bx * DD + d] = e;
}

// ---------------------------------------------------------------------------
// Kernel 4: SQKV = E @ ipw^T + ipb  (MFMA bf16, linear output, 21x6 tiles).
// ---------------------------------------------------------------------------
__global__ __launch_bounds__(256) void eqkv_gemm_kernel(
    const float* __restrict__ E, const float* __restrict__ W,
    const float* __restrict__ bias, float* __restrict__ SQKV) {
  __shared__ __align__(16) short As[128][40];
  __shared__ __align__(16) short Bs[128][40];
  const int mt = blockIdx.x / 6, nt = blockIdx.x % 6;   // 21 x 6
  const int t = threadIdx.x;
  const int wv = t >> 6, lane = t & 63, lg = lane >> 4, ln = lane & 15;
  const int wm = wv >> 1, wn = wv & 1;

  f32x4 acc[4][4];
#pragma unroll
  for (int i = 0; i < 4; ++i)
#pragma unroll
    for (int j = 0; j < 4; ++j) acc[i][j] = (f32x4){0, 0, 0, 0};

  for (int k0 = 0; k0 < DD; k0 += 32) {
    __syncthreads();
    for (int f = t; f < 1024; f += 256) {
      int row = f >> 3, q4 = (f & 7) * 4;
      float4 xa = *(const float4*)&E[(size_t)(mt * 128 + row) * DD + k0 + q4];
      float4 wa = *(const float4*)&W[(size_t)(nt * 128 + row) * DD + k0 + q4];
      short* ad = &As[row][q4];
      ad[0] = f2bf(xa.x); ad[1] = f2bf(xa.y); ad[2] = f2bf(xa.z); ad[3] = f2bf(xa.w);
      short* bd = &Bs[row][q4];
      bd[0] = f2bf(wa.x); bd[1] = f2bf(wa.y); bd[2] = f2bf(wa.z); bd[3] = f2bf(wa.w);
    }
    __syncthreads();
    bf16x8 af[4], bfr[4];
#pragma unroll
    for (int i = 0; i < 4; ++i) af[i] = *(const bf16x8*)&As[wm * 64 + i * 16 + ln][lg * 8];
#pragma unroll
    for (int j = 0; j < 4; ++j) bfr[j] = *(const bf16x8*)&Bs[wn * 64 + j * 16 + ln][lg * 8];
#pragma unroll
    for (int i = 0; i < 4; ++i)
#pragma unroll
      for (int j = 0; j < 4; ++j)
        acc[i][j] = __builtin_amdgcn_mfma_f32_16x16x32_bf16(af[i], bfr[j], acc[i][j], 0, 0, 0);
  }
#pragma unroll
  for (int i = 0; i < 4; ++i) {
#pragma unroll
    for (int j = 0; j < 4; ++j) {
      int col = nt * 128 + wn * 64 + j * 16 + ln;
      float bcol = bias[col];
#pragma unroll
      for (int r = 0; r < 4; ++r) {
        int row = mt * 128 + wm * 64 + i * 16 + lg * 4 + r;
        SQKV[(size_t)row * TRIPLE + col] = acc[i][j][r] + bcol;
      }
    }
  }
}

// ---------------------------------------------------------------------------
// Kernel 5: compressed attention (8-way key split, butterfly merge).
// FAN-IN: last block per batch (acnt==31) computes pooled output.
// ---------------------------------------------------------------------------
__global__ __launch_bounds__(256) void attn_small_kernel(
    const float* __restrict__ SQKV, const unsigned* __restrict__ npix,
    const unsigned* __restrict__ nswb, float* __restrict__ ctx_sum,
    unsigned* __restrict__ acnt, const float* __restrict__ opw,
    const float* __restrict__ opb, float* __restrict__ out_pooled) {
  const int blk = blockIdx.x;             // ((b*8)+h)*4 + qg
  const int qg = blk & 3, h = (blk >> 2) & 7, b = blk >> 5;
  const int nsb = (int)npix[b];           // <= 80
  const int D = 32 + nsb;
  const int t = threadIdx.x;
  __shared__ float Kh[DMAX][36];
  __shared__ float Vh[DMAX][36];
  __shared__ float cw[DMAX];
  __shared__ float sctx[32];
  __shared__ unsigned alast;
  __shared__ float mcp[DD];
  if (qg * 32 < D) {
    const int hoff = h * DHH;
    for (int idx = t; idx < D * 32; idx += 256) {
      int j = idx >> 5, d = idx & 31;
      int row = (j < 32) ? (PEROW + j) : (b * NTOK + j - 32);
      const float* src = &SQKV[(size_t)row * TRIPLE];
      Kh[j][d] = src[DD + hoff + d];
      Vh[j][d] = src[2 * DD + hoff + d];
    }
    if (t < D) cw[t] = (t < 32) ? (float)(32 - (int)nswb[b * 32 + t]) : 1.0f;
    if (t < 32) sctx[t] = 0.f;
    __syncthreads();
    const int q = qg * 32 + (t >> 3);     // this thread's query
    const int g = t & 7;                  // key subgroup
    const bool act = (q < D);
    float m = -1e30f, l = 0.f;
    float acc[32];
#pragma unroll
    for (int d = 0; d < 32; ++d) acc[d] = 0.f;
    if (act) {
      const float qsc = 0.25506973f;      // (1/sqrt(32)) * log2(e)
      int qrow = (q < 32) ? (PEROW + q) : (b * NTOK + q - 32);
      const float* qsrc = &SQKV[(size_t)qrow * TRIPLE];
      float qv[32];
#pragma unroll
      for (int d = 0; d < 32; ++d) qv[d] = qsrc[hoff + d] * qsc;
#pragma unroll 1
      for (int j = g; j < D; j += 8) {
        float s = 0.f;
        const float* kr = &Kh[j][0];
#pragma unroll
        for (int d = 0; d < 32; ++d) s += qv[d] * kr[d];
        float mn = fmaxf(m, s);
        float corr = exp2f(m - mn);
        float pw = cw[j] * exp2f(s - mn);
        l = l * corr + pw;
        const float* vr = &Vh[j][0];
#pragma unroll
        for (int d = 0; d < 32; ++d) acc[d] = acc[d] * corr + pw * vr[d];
        m = mn;
      }
    }
#pragma unroll
    for (int off = 1; off <= 4; off <<= 1) {
      float mo = __shfl_xor(m, off);
      float lo = __shfl_xor(l, off);
      float mm = fmaxf(m, mo);
      float fa = exp2f(m - mm), fb = exp2f(mo - mm);
      l = l * fa + lo * fb;
#pragma unroll
      for (int d = 0; d < 32; ++d) {
        float ao = __shfl_xor(acc[d], off);
        acc[d] = acc[d] * fa + ao * fb;
      }
      m = mm;
    }
    const float wq = (act && l > 0.f) ? cw[q] / l : 0.f;
#pragma unroll
    for (int d = 0; d < 32; ++d) {
      float val = wq * acc[d];
      val += __shfl_xor(val, 8);
      val += __shfl_xor(val, 16);
      val += __shfl_xor(val, 32);
      if ((t & 63) == 0) atomicAdd(&sctx[d], val);
    }
    __syncthreads();
    if (t < 32) atomicAdd(&ctx_sum[b * DD + hoff + t], sctx[t]);
  }
  // ---- fan-in: last block of batch b computes pooled ----
  __threadfence();
  if (t == 0) alast = atomicAdd(&acnt[b * 32], 1u);
  __syncthreads();
  if (alast != 31u) return;
  mcp[t] = aload_f(&ctx_sum[b * DD + t]) * (1.f / 1024.f);
  __syncthreads();
  float pacc = opb[t];
  const float* wr = opw + (size_t)t * DD;
#pragma unroll 4
  for (int d = 0; d < DD; ++d) pacc += mcp[d] * wr[d];
  out_pooled[b * DD + t] = pacc;
}

// ---------------------------------------------------------------------------
extern "C" void kernel_launch(void* const* d_in, const int* in_sizes, int n_in,
                              void* d_out, int out_size, void* d_ws, size_t ws_size,
                              hipStream_t stream) {
  const float* x = (const float*)d_in[0];
  const float* conv_w = (const float*)d_in[1];
  const float* emb = (const float*)d_in[2];
  const float* ipw = (const float*)d_in[3];
  const float* ipb = (const float*)d_in[4];
  const float* opw = (const float*)d_in[5];
  const float* opb = (const float*)d_in[6];

  float* out = (float*)d_out;
  float* out_pooled = out;                          // 32*256       = 8192
  float* out_sw = out + 8192;                       // 32*32*32*128 = 4194304
  float* out_topi = out + 8192 + 4194304;           // 32*32*32*8   = 262144

  // workspace layout (~28.8 MiB)
  char* ws = (char*)d_ws;
  float*    A      = (float*)(ws);                      // 16777216
  unsigned* ghist1 = (unsigned*)(ws + 16777216);        // 262144
  unsigned* selv   = (unsigned*)(ws + 17039360);        // 128
  unsigned* gmaxb  = (unsigned*)(ws + 17039488);        // 128
  unsigned* nswb   = (unsigned*)(ws + 17039616);        // 4096
  unsigned* npix   = (unsigned*)(ws + 17043712);        // 128
  unsigned* glist  = (unsigned*)(ws + 17043840);        // 10240
  unsigned* cnd_n  = (unsigned*)(ws + 17054080);        // 4096 (padded: 1/128B)
  unsigned* ccnt   = (unsigned*)(ws + 17058176);        // 4096
  unsigned* gcnt   = (unsigned*)(ws + 17062272);        // 4096
  unsigned* acnt   = (unsigned*)(ws + 17066368);        // 4096
  float*    candv  = (float*)(ws + 17070464);           // 262144
  unsigned* candloc= (unsigned*)(ws + 17332608);        // 262144
  int*      kidx8  = (int*)(ws + 17594752);             // 81920
  float*    kval8  = (float*)(ws + 17676672);           // 81920
  float*    E      = (float*)(ws + 17758592);           // 2752512 (2688x256x4)
  float*    SQKV   = (float*)(ws + 20511104);           // 8257536 (2688x768x4)
  float*    ctx    = (float*)(ws + 28768640);           // 32768

  zero_kernel<<<BB, 256, 0, stream>>>(ghist1, selv, gmaxb, cnd_n, ccnt, gcnt, acnt, ctx);
  conv_relu_hist_kernel<<<BB * 64, 256, 0, stream>>>(x, conv_w, A, ghist1, gmaxb,
                                                     out_topi, out_sw, ccnt, selv);
  gather_kernel<<<dim3(64, BB), 256, 0, stream>>>(A, selv, cnd_n, candv, candloc,
                                                  gcnt, gmaxb, out_sw, out_topi,
                                                  kidx8, kval8, glist, nswb, npix);
  emb_build_kernel<<<PEROW + 32, 256, 0, stream>>>(npix, kidx8, kval8, glist, emb, E);
  eqkv_gemm_kernel<<<21 * 6, 256, 0, stream>>>(E, ipw, ipb, SQKV);
  attn_small_kernel<<<BB * NHH * 4, 256, 0, stream>>>(SQKV, npix, nswb, ctx,
                                                      acnt, opw, opb, out_pooled);
}

// Round 17
// 120.375 us; speedup vs baseline: 4.0189x; 4.0189x over previous
//
#include <hip/hip_runtime.h>
#include <hip/hip_bf16.h>

// Problem constants
#define BB 32
#define C1 128
#define SS 1024        // H*W
#define DD 256
#define NHH 8
#define DHH 32
#define KSEL 66        // ceil(0.0005*128*32*32)
#define TRIPLE 768
#define NTOK 80        // sparse-token capacity per batch (>= 66 + tie margin)
#define SCAPS 128      // survivor capacity
#define CCAP 2048      // candidate capacity per batch
#define DMAX (32 + NTOK)        // 112 tokens max per batch
#define PEROW (BB * NTOK)       // 2560: index of first PE row in E/SQKV
#define SELFLAG 0x40000000u

typedef __attribute__((ext_vector_type(8))) short bf16x8;
typedef __attribute__((ext_vector_type(4))) float f32x4;

__device__ inline short f2bf(float f) {
  union { __hip_bfloat16 h; unsigned short u; } c;
  c.h = __float2bfloat16(f);
  return (short)c.u;
}
__device__ inline float pe_val(int w, int d) {
  int i2 = d >> 1;
  float dv = expf((float)(2 * i2) * (-9.210340371976184f / 256.f));
  float ang = (float)w * dv;
  return (d & 1) ? cosf(ang) : sinf(ang);
}

// ---------------------------------------------------------------------------
// Kernel 1: 9x9 conv (cross-correlation, pad 4) + ReLU.  Per-block PRIVATE
// histogram slice (plain stores -> no pre-zeroed global state) + private
// block max.  Also: default topi fill, out_sw zero, PE rows of E (bx<32).
// ---------------------------------------------------------------------------
__global__ __launch_bounds__(256) void conv_relu_hist_kernel(
    const float* __restrict__ x, const float* __restrict__ w, float* __restrict__ A,
    unsigned* __restrict__ ghist_priv, unsigned* __restrict__ gmaxpriv,
    float* __restrict__ out_topi, float* __restrict__ out_sw,
    float* __restrict__ E) {
  const int bx = blockIdx.x;              // b*64 + cpair
  const int b = bx >> 6, c0 = (bx & 63) * 2;
  __shared__ float xs[40 * 40];
  __shared__ unsigned h[2048];
  __shared__ unsigned smax;
  const int t = threadIdx.x;
  // zero out_sw: 2048 blocks x 2048 floats each
  {
    float4 z = {0.f, 0.f, 0.f, 0.f};
    float4* sw4 = (float4*)(out_sw + (size_t)bx * 2048);
    sw4[t] = z;
    sw4[t + 256] = z;
  }
  if (bx < 256) {
    int k0 = bx * 1024 + t * 4;
    float4 v = (k0 & 4) ? make_float4(4.f, 5.f, 6.f, 7.f)
                        : make_float4(0.f, 1.f, 2.f, 3.f);
    *(float4*)&out_topi[k0] = v;
  }
  if (bx < 32) E[(size_t)(PEROW + bx) * DD + t] = pe_val(bx, t);
  for (int i = t; i < 1600; i += 256) {
    int r = i / 40, cc = i - r * 40;
    int gi = r - 4, gj = cc - 4;
    float v = 0.f;
    if (gi >= 0 && gi < 32 && gj >= 0 && gj < 32) v = x[(size_t)b * 1024 + gi * 32 + gj];
    xs[i] = v;
  }
  for (int i = t; i < 2048; i += 256) h[i] = 0u;
  if (t == 0) smax = 0u;
  __syncthreads();
  const float* w0 = w + (size_t)c0 * 81;   // block-uniform -> s_load
  const float* w1 = w0 + 81;
  const int r = t >> 3, cbase = (t & 7) * 4;
  const float4* xs4 = (const float4*)xs;
  float a0 = 0.f, a1 = 0.f, a2 = 0.f, a3 = 0.f;
  float b0 = 0.f, b1 = 0.f, b2 = 0.f, b3 = 0.f;
#pragma unroll
  for (int u = 0; u < 9; ++u) {
    int base4 = (r + u) * 10 + (t & 7);
    float4 xA = xs4[base4];
    float4 xB = xs4[base4 + 1];
    float4 xC = xs4[base4 + 2];
    float xv[12] = {xA.x, xA.y, xA.z, xA.w, xB.x, xB.y, xB.z, xB.w,
                    xC.x, xC.y, xC.z, xC.w};
#pragma unroll
    for (int v = 0; v < 9; ++v) {
      float f0 = w0[u * 9 + v], f1 = w1[u * 9 + v];
      a0 += f0 * xv[v];     a1 += f0 * xv[v + 1];
      a2 += f0 * xv[v + 2]; a3 += f0 * xv[v + 3];
      b0 += f1 * xv[v];     b1 += f1 * xv[v + 1];
      b2 += f1 * xv[v + 2]; b3 += f1 * xv[v + 3];
    }
  }
  a0 = fmaxf(a0, 0.f); a1 = fmaxf(a1, 0.f); a2 = fmaxf(a2, 0.f); a3 = fmaxf(a3, 0.f);
  b0 = fmaxf(b0, 0.f); b1 = fmaxf(b1, 0.f); b2 = fmaxf(b2, 0.f); b3 = fmaxf(b3, 0.f);
  float4 va = {a0, a1, a2, a3}, vb = {b0, b1, b2, b3};
  *(float4*)&A[((size_t)(b * C1 + c0) << 10) + r * 32 + cbase] = va;
  *(float4*)&A[((size_t)(b * C1 + c0 + 1) << 10) + r * 32 + cbase] = vb;
  unsigned lmax = 0u;
#pragma unroll
  for (int k = 0; k < 8; ++k) {
    float f = (k == 0) ? a0 : (k == 1) ? a1 : (k == 2) ? a2 : (k == 3) ? a3
            : (k == 4) ? b0 : (k == 5) ? b1 : (k == 6) ? b2 : b3;
    unsigned bits = __float_as_uint(f);
    if (bits > lmax) lmax = bits;
    if (bits >= (1u << 21)) atomicAdd(&h[bits >> 21], 1u);
  }
  atomicMax(&smax, lmax);
  __syncthreads();
  // write private histogram slice (plain coalesced stores)
  {
    uint4* dst = (uint4*)(ghist_priv + (size_t)bx * 2048);
    const uint4* src = (const uint4*)h;
    dst[t] = src[t];
    dst[t + 256] = src[t + 256];
  }
  if (t == 0) gmaxpriv[bx] = smax;
}

// ---------------------------------------------------------------------------
// Kernel 2: sum 64 private hist slices + level-1 radix pick via suffix scan.
// Also reduces per-block maxima, zeroes ctx and cnd_n for this batch.
// ---------------------------------------------------------------------------
__global__ __launch_bounds__(1024) void sel_kernel(
    const unsigned* __restrict__ ghist_priv, const unsigned* __restrict__ gmaxpriv,
    unsigned* __restrict__ selv, unsigned* __restrict__ gmaxb,
    unsigned* __restrict__ cnd_n, float* __restrict__ ctx) {
  const int b = blockIdx.x, t = threadIdx.x;
  __shared__ unsigned hl[2048];
  __shared__ unsigned sfx[1024];
  __shared__ unsigned gmx;
  if (t < 256) ctx[b * DD + t] = 0.f;
  if (t == 0) { cnd_n[b * 32] = 0u; gmx = 0u; }
  __syncthreads();
  if (t < 64) atomicMax(&gmx, gmaxpriv[b * 64 + t]);
  // sum the 64 private slices for bins t and t+1024
  {
    const unsigned* base = ghist_priv + (size_t)b * 64 * 2048;
    unsigned s0 = 0, s1 = 0;
#pragma unroll 4
    for (int s = 0; s < 64; ++s) {
      s0 += base[s * 2048 + t];
      s1 += base[s * 2048 + t + 1024];
    }
    hl[t] = s0;
    hl[t + 1024] = s1;
  }
  __syncthreads();
  if (t == 0) gmaxb[b] = gmx;
  unsigned r = (unsigned)KSEL;
  sfx[t] = hl[2 * t] + hl[2 * t + 1];
  __syncthreads();
  for (int off = 1; off < 1024; off <<= 1) {
    unsigned v = (t + off < 1024) ? sfx[t + off] : 0u;
    __syncthreads();
    sfx[t] += v;
    __syncthreads();
  }
  if (sfx[0] < r) {
    if (t == 0) selv[b] = SELFLAG;
    return;
  }
  unsigned Snext = (t < 1023) ? sfx[t + 1] : 0u;
  unsigned hi = hl[2 * t + 1], lo = hl[2 * t];
  if (Snext < r && Snext + hi >= r) selv[b] = (unsigned)(2 * t + 1);
  else if (Snext + hi < r && Snext + hi + lo >= r) selv[b] = (unsigned)(2 * t);
}

// ---------------------------------------------------------------------------
// Kernel 3: candidate gather with BLOCK-AGGREGATED compaction.
// ---------------------------------------------------------------------------
__global__ __launch_bounds__(256) void gather_kernel(
    const float* __restrict__ A, const unsigned* __restrict__ selv,
    unsigned* __restrict__ cnd_n, float* __restrict__ candv,
    unsigned* __restrict__ candloc) {
  const int b = blockIdx.y, slice = blockIdx.x, t = threadIdx.x;  // slice 0..63
  const unsigned v1 = selv[b];
  if (v1 == SELFLAG) return;
  const unsigned thr = v1 << 21;          // bits>>21 >= v1  <=>  bits >= thr
  __shared__ float lv[512];
  __shared__ unsigned ll[512];
  __shared__ unsigned lcnt, gbase;
  if (t == 0) lcnt = 0u;
  __syncthreads();
  const float4* Ab = (const float4*)(A + (size_t)b * (C1 * SS) + slice * 2048);
  const float4 va = Ab[t];
  const float4 vb = Ab[t + 256];
  const int base = slice * 2048 + t * 4;
  const float f[8] = {va.x, va.y, va.z, va.w, vb.x, vb.y, vb.z, vb.w};
#pragma unroll
  for (int c = 0; c < 8; ++c) {
    if (__float_as_uint(f[c]) >= thr) {
      unsigned loc = (unsigned)(base + (c < 4 ? c : 1020 + c));   // c*1024 + p
      unsigned s = atomicAdd(&lcnt, 1u);
      if (s < 512u) {
        lv[s] = f[c];
        ll[s] = loc;
      } else {                             // overflow spill (degenerate inputs)
        unsigned g = atomicAdd(&cnd_n[b * 32], 1u);
        if (g < (unsigned)CCAP) {
          candv[b * CCAP + g] = f[c];
          candloc[b * CCAP + g] = loc;
        }
      }
    }
  }
  __syncthreads();
  const unsigned cnt = lcnt < 512u ? lcnt : 512u;
  if (t == 0 && cnt) gbase = atomicAdd(&cnd_n[b * 32], cnt);
  __syncthreads();
  for (unsigned u = t; u < cnt; u += 256) {
    unsigned s = gbase + u;
    if (s < (unsigned)CCAP) {
      candv[b * CCAP + s] = lv[u];
      candloc[b * CCAP + s] = ll[u];
    }
  }
}

// ---------------------------------------------------------------------------
// Kernel 4: fully-parallel sparse-pixel processing (rank-count survivors,
// bitmap slots, direct scatter of topi / sw / kidx8 / kval8).
// ---------------------------------------------------------------------------
__global__ __launch_bounds__(256) void sparse_pixels_kernel(
    const unsigned* __restrict__ cnd_n, const float* __restrict__ candv,
    const unsigned* __restrict__ candloc, const unsigned* __restrict__ selv,
    const float* __restrict__ gmaxp, float* __restrict__ out_sw,
    float* __restrict__ out_topi, int* __restrict__ kidx8,
    float* __restrict__ kval8, unsigned* __restrict__ glist,
    unsigned* __restrict__ nswb, unsigned* __restrict__ npix) {
  const int b = blockIdx.x, t = threadIdx.x;
  __shared__ float cv[CCAP];
  __shared__ unsigned cl[CCAP];
  __shared__ float sv[SCAPS];
  __shared__ int sch[SCAPS], spx[SCAPS];
  __shared__ int s_n_sh;
  __shared__ unsigned pixbit[32];
  __shared__ int mcount[NTOK];
  __shared__ int leadp[NTOK];
  if (t == 0) s_n_sh = 0;
  if (t < 32) pixbit[t] = 0u;
  unsigned n = cnd_n[b * 32];
  if (n > (unsigned)CCAP) n = (unsigned)CCAP;
  const bool ok = (selv[b] != SELFLAG) && (n >= (unsigned)KSEL);
  for (unsigned i = t; i < n; i += 256) {
    cv[i] = candv[b * CCAP + i];
    cl[i] = candloc[b * CCAP + i];
  }
  __syncthreads();
  if (ok) {
    for (unsigned i = t; i < n; i += 256) {
      float v = cv[i];
      int g = 0;
      for (unsigned j = 0; j < n; ++j) g += (cv[j] > v);
      if (g < KSEL) {
        int k = atomicAdd(&s_n_sh, 1);
        if (k < SCAPS) {
          sv[k] = v;
          sch[k] = (int)(cl[i] >> 10);
          spx[k] = (int)(cl[i] & 1023u);
        }
      }
    }
  }
  __syncthreads();
  const int s_n = s_n_sh < SCAPS ? s_n_sh : SCAPS;
  for (int i = t; i < s_n; i += 256)
    atomicOr(&pixbit[spx[i] >> 5], 1u << (spx[i] & 31));
  __syncthreads();
  if (t == 0) {
    int np = 0;
#pragma unroll
    for (int wd = 0; wd < 32; ++wd) np += __popc(pixbit[wd]);
    npix[b] = (unsigned)(np < NTOK ? np : NTOK);
  }
  if (t < 32) {
    unsigned cnt = 0;
#pragma unroll
    for (int rr = 0; rr < 32; ++rr) cnt += (pixbit[rr] >> t) & 1u;
    nswb[b * 32 + t] = cnt;
  }
  const float gm = gmaxp[b];
  const float scale = gm > 0.f ? 1.f / gm : 0.f;
  __syncthreads();
  for (int i = t; i < s_n; i += 256) {
    const int p = spx[i];
    const float v = sv[i];
    const int c = sch[i];
    const int word = p >> 5, bit = p & 31;
    int slot = 0;
    for (int wd = 0; wd < word; ++wd) slot += __popc(pixbit[wd]);
    slot += __popc(pixbit[word] & (bit ? ((1u << bit) - 1u) : 0u));
    if (slot >= NTOK) continue;
    int rank = 0, cntp = 0;
    for (int j = 0; j < s_n; ++j) {
      if (spx[j] != p) continue;
      ++cntp;
      rank += (sv[j] > v || (sv[j] == v && sch[j] < c));
    }
    const size_t pix = (size_t)b * SS + p;
    const float sval = v * scale;
    if (rank < 8) {
      out_topi[pix * 8 + rank] = (float)c;
      out_sw[pix * C1 + c] = sval;
      kidx8[((size_t)b * NTOK + slot) * 8 + rank] = c;
      kval8[((size_t)b * NTOK + slot) * 8 + rank] = sval;
    }
    if (rank == 0) {
      glist[b * NTOK + slot] =
          ((unsigned)b << 16) | ((unsigned)slot << 8) | (unsigned)(p & 31);
      mcount[slot] = cntp < 8 ? cntp : 8;
      leadp[slot] = p;
    }
  }
  __syncthreads();
  const int np = (int)npix[b];
  for (int s = t; s < np; s += 256) {
    const int m = mcount[s];
    if (m >= 8) continue;
    const int p = leadp[s];
    int used[8];
    for (int k = 0; k < m; ++k) used[k] = kidx8[((size_t)b * NTOK + s) * 8 + k];
    int fill_c = 0;
    for (int j = m; j < 8; ++j) {
      bool adv = true;
      while (adv) {
        adv = false;
        for (int k = 0; k < m; ++k)
          if (used[k] == fill_c) adv = true;
        if (adv) ++fill_c;
      }
      kidx8[((size_t)b * NTOK + s) * 8 + j] = fill_c;
      kval8[((size_t)b * NTOK + s) * 8 + j] = 0.f;
      out_topi[((size_t)b * SS + p) * 8 + j] = (float)fill_c;
      ++fill_c;
    }
  }
}

// ---------------------------------------------------------------------------
// Kernel 5: E sparse-token rows: PE(w) + sum_j kval8[j]*emb[kidx8[j]].
// (PE rows PEROW..PEROW+31 are written by the conv kernel.)
// ---------------------------------------------------------------------------
__global__ __launch_bounds__(256) void emb_build_kernel(
    const unsigned* __restrict__ npix, const int* __restrict__ kidx8,
    const float* __restrict__ kval8, const unsigned* __restrict__ glist,
    const float* __restrict__ emb, float* __restrict__ E) {
  const int bx = blockIdx.x;              // b*NTOK + i
  const int d = threadIdx.x;
  const int b = bx / NTOK, i = bx - b * NTOK;
  if ((unsigned)i >= npix[b]) return;
  const int w = (int)(glist[bx] & 255u);
  const int* ki = kidx8 + (size_t)bx * 8;
  const float* kv = kval8 + (size_t)bx * 8;
  float e = pe_val(w, d);
#pragma unroll
  for (int j = 0; j < 8; ++j) e += kv[j] * emb[(size_t)ki[j] * DD + d];
  E[(size_t)bx * DD + d] = e;
}

// ---------------------------------------------------------------------------
// Kernel 6: SQKV = E @ ipw^T + ipb  (MFMA bf16, linear output, 21x6 tiles).
// ---------------------------------------------------------------------------
__global__ __launch_bounds__(256) void eqkv_gemm_kernel(
    const float* __restrict__ E, const float* __restrict__ W,
    const float* __restrict__ bias, float* __restrict__ SQKV) {
  __shared__ __align__(16) short As[128][40];
  __shared__ __align__(16) short Bs[128][40];
  const int mt = blockIdx.x / 6, nt = blockIdx.x % 6;   // 21 x 6
  const int t = threadIdx.x;
  const int wv = t >> 6, lane = t & 63, lg = lane >> 4, ln = lane & 15;
  const int wm = wv >> 1, wn = wv & 1;

  f32x4 acc[4][4];
#pragma unroll
  for (int i = 0; i < 4; ++i)
#pragma unroll
    for (int j = 0; j < 4; ++j) acc[i][j] = (f32x4){0, 0, 0, 0};

  for (int k0 = 0; k0 < DD; k0 += 32) {
    __syncthreads();
    for (int f = t; f < 1024; f += 256) {
      int row = f >> 3, q4 = (f & 7) * 4;
      float4 xa = *(const float4*)&E[(size_t)(mt * 128 + row) * DD + k0 + q4];
      float4 wa = *(const float4*)&W[(size_t)(nt * 128 + row) * DD + k0 + q4];
      short* ad = &As[row][q4];
      ad[0] = f2bf(xa.x); ad[1] = f2bf(xa.y); ad[2] = f2bf(xa.z); ad[3] = f2bf(xa.w);
      short* bd = &Bs[row][q4];
      bd[0] = f2bf(wa.x); bd[1] = f2bf(wa.y); bd[2] = f2bf(wa.z); bd[3] = f2bf(wa.w);
    }
    __syncthreads();
    bf16x8 af[4], bfr[4];
#pragma unroll
    for (int i = 0; i < 4; ++i) af[i] = *(const bf16x8*)&As[wm * 64 + i * 16 + ln][lg * 8];
#pragma unroll
    for (int j = 0; j < 4; ++j) bfr[j] = *(const bf16x8*)&Bs[wn * 64 + j * 16 + ln][lg * 8];
#pragma unroll
    for (int i = 0; i < 4; ++i)
#pragma unroll
      for (int j = 0; j < 4; ++j)
        acc[i][j] = __builtin_amdgcn_mfma_f32_16x16x32_bf16(af[i], bfr[j], acc[i][j], 0, 0, 0);
  }
#pragma unroll
  for (int i = 0; i < 4; ++i) {
#pragma unroll
    for (int j = 0; j < 4; ++j) {
      int col = nt * 128 + wn * 64 + j * 16 + ln;
      float bcol = bias[col];
#pragma unroll
      for (int r = 0; r < 4; ++r) {
        int row = mt * 128 + wm * 64 + i * 16 + lg * 4 + r;
        SQKV[(size_t)row * TRIPLE + col] = acc[i][j][r] + bcol;
      }
    }
  }
}

// ---------------------------------------------------------------------------
// Kernel 7: compressed attention.  Block = (b, h, 32-query group); key loop
// split 8 ways across lanes with shfl_xor butterfly online-softmax merge.
// ---------------------------------------------------------------------------
__global__ __launch_bounds__(256) void attn_small_kernel(
    const float* __restrict__ SQKV, const unsigned* __restrict__ npix,
    const unsigned* __restrict__ nswb, float* __restrict__ ctx_sum) {
  const int blk = blockIdx.x;             // ((b*8)+h)*4 + qg
  const int qg = blk & 3, h = (blk >> 2) & 7, b = blk >> 5;
  const int nsb = (int)npix[b];           // <= 80
  const int D = 32 + nsb;
  if (qg * 32 >= D) return;
  const int t = threadIdx.x;
  __shared__ float Kh[DMAX][36];
  __shared__ float Vh[DMAX][36];
  __shared__ float cw[DMAX];
  __shared__ float sctx[32];
  const int hoff = h * DHH;
  for (int idx = t; idx < D * 32; idx += 256) {
    int j = idx >> 5, d = idx & 31;
    int row = (j < 32) ? (PEROW + j) : (b * NTOK + j - 32);
    const float* src = &SQKV[(size_t)row * TRIPLE];
    Kh[j][d] = src[DD + hoff + d];
    Vh[j][d] = src[2 * DD + hoff + d];
  }
  if (t < D) cw[t] = (t < 32) ? (float)(32 - (int)nswb[b * 32 + t]) : 1.0f;
  if (t < 32) sctx[t] = 0.f;
  __syncthreads();

  const int q = qg * 32 + (t >> 3);       // this thread's query
  const int g = t & 7;                    // key subgroup
  const bool act = (q < D);
  float m = -1e30f, l = 0.f;
  float acc[32];
#pragma unroll
  for (int d = 0; d < 32; ++d) acc[d] = 0.f;
  if (act) {
    const float qsc = 0.25506973f;        // (1/sqrt(32)) * log2(e)
    int qrow = (q < 32) ? (PEROW + q) : (b * NTOK + q - 32);
    const float* qsrc = &SQKV[(size_t)qrow * TRIPLE];
    float qv[32];
#pragma unroll
    for (int d = 0; d < 32; ++d) qv[d] = qsrc[hoff + d] * qsc;
#pragma unroll 1
    for (int j = g; j < D; j += 8) {
      float s = 0.f;
      const float* kr = &Kh[j][0];
#pragma unroll
      for (int d = 0; d < 32; ++d) s += qv[d] * kr[d];
      float mn = fmaxf(m, s);
      float corr = exp2f(m - mn);
      float pw = cw[j] * exp2f(s - mn);
      l = l * corr + pw;
      const float* vr = &Vh[j][0];
#pragma unroll
      for (int d = 0; d < 32; ++d) acc[d] = acc[d] * corr + pw * vr[d];
      m = mn;
    }
  }
#pragma unroll
  for (int off = 1; off <= 4; off <<= 1) {
    float mo = __shfl_xor(m, off);
    float lo = __shfl_xor(l, off);
    float mm = fmaxf(m, mo);
    float fa = exp2f(m - mm), fb = exp2f(mo - mm);
    l = l * fa + lo * fb;
#pragma unroll
    for (int d = 0; d < 32; ++d) {
      float ao = __shfl_xor(acc[d], off);
      acc[d] = acc[d] * fa + ao * fb;
    }
    m = mm;
  }
  const float wq = (act && l > 0.f) ? cw[q] / l : 0.f;
#pragma unroll
  for (int d = 0; d < 32; ++d) {
    float val = wq * acc[d];
    val += __shfl_xor(val, 8);
    val += __shfl_xor(val, 16);
    val += __shfl_xor(val, 32);
    if ((t & 63) == 0) atomicAdd(&sctx[d], val);
  }
  __syncthreads();
  if (t < 32) atomicAdd(&ctx_sum[b * DD + hoff + t], sctx[t]);
}

// ---------------------------------------------------------------------------
// Kernel 8: pooled(b,o) = bias[o] + sum_d (ctx_sum[b,d]/1024) * Wout[o,d]
// ---------------------------------------------------------------------------
__global__ __launch_bounds__(256) void pooled_kernel(
    const float* __restrict__ ctx_sum, const float* __restrict__ Wout,
    const float* __restrict__ bout, float* __restrict__ out) {
  const int b = blockIdx.x;
  const int o = threadIdx.x;
  __shared__ float mc[DD];
  mc[o] = ctx_sum[b * DD + o] * (1.f / 1024.f);
  __syncthreads();
  float acc = bout[o];
  const float* wr = Wout + (size_t)o * DD;
#pragma unroll 4
  for (int d = 0; d < DD; ++d) acc += mc[d] * wr[d];
  out[b * DD + o] = acc;
}

// ---------------------------------------------------------------------------
extern "C" void kernel_launch(void* const* d_in, const int* in_sizes, int n_in,
                              void* d_out, int out_size, void* d_ws, size_t ws_size,
                              hipStream_t stream) {
  const float* x = (const float*)d_in[0];
  const float* conv_w = (const float*)d_in[1];
  const float* emb = (const float*)d_in[2];
  const float* ipw = (const float*)d_in[3];
  const float* ipb = (const float*)d_in[4];
  const float* opw = (const float*)d_in[5];
  const float* opb = (const float*)d_in[6];

  float* out = (float*)d_out;
  float* out_pooled = out;                          // 32*256       = 8192
  float* out_sw = out + 8192;                       // 32*32*32*128 = 4194304
  float* out_topi = out + 8192 + 4194304;           // 32*32*32*8   = 262144

  // workspace layout (~45 MiB)
  char* ws = (char*)d_ws;
  float*    A       = (float*)(ws);                     // 16777216
  unsigned* ghist_p = (unsigned*)(ws + 16777216);       // 16777216 (2048x2048x4)
  unsigned* gmaxpriv= (unsigned*)(ws + 33554432);       // 8192
  unsigned* selv    = (unsigned*)(ws + 33562624);       // 128
  unsigned* gmaxb   = (unsigned*)(ws + 33562752);       // 128
  unsigned* nswb    = (unsigned*)(ws + 33562880);       // 4096
  unsigned* npix    = (unsigned*)(ws + 33566976);       // 128
  unsigned* glist   = (unsigned*)(ws + 33567104);       // 10240
  unsigned* cnd_n   = (unsigned*)(ws + 33577344);       // 4096 (padded: 1/128B)
  float*    candv   = (float*)(ws + 33581440);          // 262144
  unsigned* candloc = (unsigned*)(ws + 33843584);       // 262144
  int*      kidx8   = (int*)(ws + 34105728);            // 81920
  float*    kval8   = (float*)(ws + 34187648);          // 81920
  float*    E       = (float*)(ws + 34269568);          // 2752512 (2688x256x4)
  float*    SQKV    = (float*)(ws + 37022080);          // 8257536 (2688x768x4)
  float*    ctx     = (float*)(ws + 45279616);          // 32768

  conv_relu_hist_kernel<<<BB * 64, 256, 0, stream>>>(x, conv_w, A, ghist_p, gmaxpriv,
                                                     out_topi, out_sw, E);
  sel_kernel<<<BB, 1024, 0, stream>>>(ghist_p, gmaxpriv, selv, gmaxb, cnd_n, ctx);
  gather_kernel<<<dim3(64, BB), 256, 0, stream>>>(A, selv, cnd_n, candv, candloc);
  sparse_pixels_kernel<<<BB, 256, 0, stream>>>(cnd_n, candv, candloc, selv,
                                               (const float*)gmaxb, out_sw, out_topi,
                                               kidx8, kval8, glist, nswb, npix);
  emb_build_kernel<<<PEROW, 256, 0, stream>>>(npix, kidx8, kval8, glist, emb, E);
  eqkv_gemm_kernel<<<21 * 6, 256, 0, stream>>>(E, ipw, ipb, SQKV);
  attn_small_kernel<<<BB * NHH * 4, 256, 0, stream>>>(SQKV, npix, nswb, ctx);
  pooled_kernel<<<BB, 256, 0, stream>>>(ctx, opw, opb, out_pooled);
}